// Round 8
// baseline (185.677 us; speedup 1.0000x reference)
//
#include <hip/hip_runtime.h>
#include <hip/hip_bf16.h>
#include <cstdint>

#define D 128

typedef __attribute__((ext_vector_type(8))) short short8v;
typedef __attribute__((ext_vector_type(4))) float float4v;
typedef __attribute__((ext_vector_type(4))) unsigned int uint4v;

__device__ __forceinline__ float bf2f(unsigned short u) {
    union { unsigned int i; float f; } x; x.i = ((unsigned int)u) << 16; return x.f;
}
__device__ __forceinline__ unsigned short f2bf(float f) {
    union { float f; unsigned int i; } x; x.f = f;
    unsigned int r = x.i + 0x7FFFu + ((x.i >> 16) & 1u);
    return (unsigned short)(r >> 16);
}

__device__ __forceinline__ void detect_body(const int* __restrict__ eidx, int nPairs,
                                            int* __restrict__ flag) {
    __shared__ int anyNZ;
    if (threadIdx.x == 0) anyNZ = 0;
    __syncthreads();
    int cnt = nPairs < 2048 ? nPairs : 2048;
    int local = 0;
    for (int i = threadIdx.x; i < cnt; i += 256)
        if (eidx[2 * i + 1] != 0) local = 1;
    if (local) anyNZ = 1;
    __syncthreads();
    if (threadIdx.x == 0) *flag = (anyNZ == 0) ? 1 : 0;
}

// blocks 0..127: W1 (fp32) -> Bc (bf16 [n=256][k=128]);
// block 128: W2 -> W2b (bf16 [16 cols][128 k], cols>=2 zero) + int64 detect;
// blocks 129..: X (fp32) -> Xb (bf16), streaming.
__global__ __launch_bounds__(256) void prep(
    const float* __restrict__ X, const float* __restrict__ W1,
    const float* __restrict__ W2,
    unsigned short* __restrict__ Bc, unsigned short* __restrict__ W2b,
    unsigned short* __restrict__ Xb,
    const int* __restrict__ eidx, int nPairs, int* __restrict__ flag, int nChunks)
{
    const int b = blockIdx.x;
    if (b < 128) {
        int i = b * 256 + threadIdx.x;
        int n = i >> 7, k = i & 127;
        Bc[i] = f2bf(W1[(size_t)((n < 128) ? k : k + 128) * D + (n & 127)]);
    } else if (b == 128) {
        const int base = threadIdx.x * 8;           // 2048 = 16*128 elems
#pragma unroll
        for (int j = 0; j < 8; ++j) {
            int idx = base + j;
            int c = idx >> 7, k = idx & 127;
            W2b[idx] = (c < 2) ? f2bf(W2[k * 2 + c]) : (unsigned short)0;
        }
        detect_body(eidx, nPairs, flag);
    } else {
        int c = (b - 129) * 256 + threadIdx.x;
        if (c < nChunks) {
            const float* p = X + (size_t)c * 8;
            float4 x0 = *reinterpret_cast<const float4*>(p);
            float4 x1 = *reinterpret_cast<const float4*>(p + 4);
            short8v o;
            o[0] = (short)f2bf(x0.x); o[1] = (short)f2bf(x0.y);
            o[2] = (short)f2bf(x0.z); o[3] = (short)f2bf(x0.w);
            o[4] = (short)f2bf(x1.x); o[5] = (short)f2bf(x1.y);
            o[6] = (short)f2bf(x1.z); o[7] = (short)f2bf(x1.w);
            *reinterpret_cast<short8v*>(Xb + (size_t)c * 8) = o;
        }
    }
}

// U|V = Xb @ W1 via bf16 MFMA, swapped operands; 64 nodes x 256 cols per block
// (grid no longer caps occupancy: 1563 blocks -> VGPR-limited residency).
// B force-hoisted, A depth-1 prefetched, b1 folded into acc init.
__global__ __launch_bounds__(256, 4) void uv_mfma(
    const unsigned short* __restrict__ Xb, const unsigned short* __restrict__ Bc,
    const float* __restrict__ b1,
    unsigned short* __restrict__ U, unsigned short* __restrict__ V, int nNodes)
{
    const int t = threadIdx.x;
    const int wave = t >> 6;
    const int l = t & 63;
    const int lr = l & 15;          // node lane / B-col lane
    const int lk = l >> 4;          // k-group lane
    const int n0w = wave * 64;      // this wave's output-col base (0..255)

    short8v bf[4][4];
#pragma unroll
    for (int nt = 0; nt < 4; ++nt)
#pragma unroll
        for (int ks = 0; ks < 4; ++ks)
            bf[nt][ks] = *reinterpret_cast<const short8v*>(
                Bc + (size_t)(n0w + nt * 16 + lr) * D + ks * 32 + lk * 8);
#pragma unroll
    for (int nt = 0; nt < 4; ++nt)
#pragma unroll
        for (int ks = 0; ks < 4; ++ks)
            asm volatile("" : "+v"(bf[nt][ks]));

    // bias for this lane's output cols (0 for V-columns); folded into acc init
    float4 bvv[4];
#pragma unroll
    for (int nt = 0; nt < 4; ++nt) {
        if (n0w < 128)
            bvv[nt] = *reinterpret_cast<const float4*>(b1 + n0w + nt * 16 + lk * 4);
        else
            bvv[nt] = make_float4(0.f, 0.f, 0.f, 0.f);
    }

    int row = blockIdx.x * 64 + lr;
    const unsigned short* xbase = Xb + lk * 8;

    short8v aC[4], aN[4];
    {
        const unsigned short* p = xbase + (size_t)min(row, nNodes - 1) * D;
#pragma unroll
        for (int ks = 0; ks < 4; ++ks)
            aC[ks] = *reinterpret_cast<const short8v*>(p + ks * 32);
    }

#pragma unroll
    for (int mt = 0; mt < 4; ++mt) {
        if (mt < 3) {
            const unsigned short* p = xbase + (size_t)min(row + 16, nNodes - 1) * D;
#pragma unroll
            for (int ks = 0; ks < 4; ++ks)
                aN[ks] = *reinterpret_cast<const short8v*>(p + ks * 32);
        }
        float4v acc[4];
#pragma unroll
        for (int nt = 0; nt < 4; ++nt) {
            acc[nt] = (float4v){bvv[nt].x, bvv[nt].y, bvv[nt].z, bvv[nt].w};
#pragma unroll
            for (int ks = 0; ks < 4; ++ks)
                acc[nt] = __builtin_amdgcn_mfma_f32_16x16x32_bf16(
                    bf[nt][ks], aC[ks], acc[nt], 0, 0, 0);
        }
        if (row < nNodes) {
            unsigned short* base = (n0w < 128 ? U : V) + (size_t)row * D + (n0w & 127);
#pragma unroll
            for (int nt = 0; nt < 4; ++nt) {
                ushort4 o;
                o.x = f2bf(acc[nt][0]); o.y = f2bf(acc[nt][1]);
                o.z = f2bf(acc[nt][2]); o.w = f2bf(acc[nt][3]);
                *reinterpret_cast<ushort4*>(base + nt * 16 + lk * 4) = o;
            }
        }
        row += 16;
#pragma unroll
        for (int ks = 0; ks < 4; ++ks) aC[ks] = aN[ks];
    }
}

// Mid-tier fallback (no Xb): fp32 X + in-kernel cvt, b1 folded.
__global__ __launch_bounds__(256, 3) void uv_mfma_f32(
    const float* __restrict__ X, const unsigned short* __restrict__ Bc,
    const float* __restrict__ b1,
    unsigned short* __restrict__ U, unsigned short* __restrict__ V, int nNodes)
{
    const int t = threadIdx.x;
    const int wave = t >> 6;
    const int l = t & 63;
    const int lr = l & 15;
    const int lk = l >> 4;
    const int n0w = wave * 64;

    short8v bf[4][4];
#pragma unroll
    for (int nt = 0; nt < 4; ++nt)
#pragma unroll
        for (int ks = 0; ks < 4; ++ks)
            bf[nt][ks] = *reinterpret_cast<const short8v*>(
                Bc + (size_t)(n0w + nt * 16 + lr) * D + ks * 32 + lk * 8);

    float4 bvv[4];
#pragma unroll
    for (int nt = 0; nt < 4; ++nt) {
        if (n0w < 128)
            bvv[nt] = *reinterpret_cast<const float4*>(b1 + n0w + nt * 16 + lk * 4);
        else
            bvv[nt] = make_float4(0.f, 0.f, 0.f, 0.f);
    }

    int row = blockIdx.x * 64 + lr;
    float4 xr[8];
    {
        const float* xp = X + (size_t)min(row, nNodes - 1) * D + lk * 8;
#pragma unroll
        for (int ks = 0; ks < 4; ++ks) {
            xr[2 * ks]     = *reinterpret_cast<const float4*>(xp + ks * 32);
            xr[2 * ks + 1] = *reinterpret_cast<const float4*>(xp + ks * 32 + 4);
        }
    }
#pragma unroll
    for (int mt = 0; mt < 4; ++mt) {
        short8v af[4];
#pragma unroll
        for (int ks = 0; ks < 4; ++ks) {
            const float4 x0 = xr[2 * ks], x1 = xr[2 * ks + 1];
            short8v a;
            a[0] = (short)f2bf(x0.x); a[1] = (short)f2bf(x0.y);
            a[2] = (short)f2bf(x0.z); a[3] = (short)f2bf(x0.w);
            a[4] = (short)f2bf(x1.x); a[5] = (short)f2bf(x1.y);
            a[6] = (short)f2bf(x1.z); a[7] = (short)f2bf(x1.w);
            af[ks] = a;
        }
        if (mt < 3) {
            const float* np = X + (size_t)min(row + 16, nNodes - 1) * D + lk * 8;
#pragma unroll
            for (int ks = 0; ks < 4; ++ks) {
                xr[2 * ks]     = *reinterpret_cast<const float4*>(np + ks * 32);
                xr[2 * ks + 1] = *reinterpret_cast<const float4*>(np + ks * 32 + 4);
            }
        }
        float4v acc[4];
#pragma unroll
        for (int nt = 0; nt < 4; ++nt) {
            acc[nt] = (float4v){bvv[nt].x, bvv[nt].y, bvv[nt].z, bvv[nt].w};
#pragma unroll
            for (int ks = 0; ks < 4; ++ks)
                acc[nt] = __builtin_amdgcn_mfma_f32_16x16x32_bf16(
                    bf[nt][ks], af[ks], acc[nt], 0, 0, 0);
        }
        if (row < nNodes) {
            unsigned short* base = (n0w < 128 ? U : V) + (size_t)row * D + (n0w & 127);
#pragma unroll
            for (int nt = 0; nt < 4; ++nt) {
                ushort4 o;
                o.x = f2bf(acc[nt][0]); o.y = f2bf(acc[nt][1]);
                o.z = f2bf(acc[nt][2]); o.w = f2bf(acc[nt][3]);
                *reinterpret_cast<ushort4*>(base + nt * 16 + lk * 4) = o;
            }
        }
        row += 16;
    }
}

// MFMA edge kernel: one wave = 16 edges. Lane l gathers edge (l&15),
// dim-chunk (l>>4) of U[si], V[di] (4x16B each). h = relu(u+v) packed via
// v_cvt_pk_bf16_f32; projection+reduction = 4 MFMAs against W2b panel.
// s0,s1 land in acc[0],acc[1] of lanes lk==0 (col = edge) -> sigmoid, store.
__global__ __launch_bounds__(256, 4) void edge_attn(
    const int* __restrict__ eidx, const unsigned short* __restrict__ U,
    const unsigned short* __restrict__ V, const unsigned short* __restrict__ W2b,
    const float* __restrict__ b2, const int* __restrict__ i64flag,
    float* __restrict__ out, int nEdges, int nNodes)
{
    const int t = threadIdx.x;
    const int wave = t >> 6;
    const int l = t & 63;
    const int lr = l & 15;          // edge lane
    const int lk = l >> 4;          // dim-chunk lane
    const int ebase = (blockIdx.x * 4 + wave) * 16;
    if (ebase >= nEdges) return;
    const int is64 = *i64flag;

    const int e = ebase + lr;
    const int ec = min(e, nEdges - 1);
    int si = eidx[is64 ? (size_t)2 * ec : (size_t)ec];
    int di = eidx[is64 ? 2 * ((size_t)nEdges + ec) : (size_t)nEdges + ec];
    const unsigned nmax = (unsigned)(nNodes - 1);
    const unsigned uoff = (min((unsigned)si, nmax) << 8) + ((unsigned)lk << 4);
    const unsigned voff = (min((unsigned)di, nmax) << 8) + ((unsigned)lk << 4);

    uint4v u[4], v[4];
#pragma unroll
    for (int ks = 0; ks < 4; ++ks)
        u[ks] = *reinterpret_cast<const uint4v*>((const char*)U + uoff + ks * 64);
#pragma unroll
    for (int ks = 0; ks < 4; ++ks)
        v[ks] = *reinterpret_cast<const uint4v*>((const char*)V + voff + ks * 64);
#pragma unroll
    for (int ks = 0; ks < 4; ++ks) {
        asm volatile("" : "+v"(u[ks]));
        asm volatile("" : "+v"(v[ks]));
    }

    // B-frag: lane lr holds W2 col lr (cols >= 2 are zero)
    short8v wb[4];
#pragma unroll
    for (int ks = 0; ks < 4; ++ks)
        wb[ks] = *reinterpret_cast<const short8v*>(W2b + lr * D + ks * 32 + lk * 8);

    const float bb0 = b2[0], bb1 = b2[1];

    // h = relu(u+v) -> packed bf16 A-frag (cvt_pk: 1 instr / 2 dims)
    short8v pa[4];
#pragma unroll
    for (int ks = 0; ks < 4; ++ks) {
        const unsigned short* up = reinterpret_cast<const unsigned short*>(&u[ks]);
        const unsigned short* vp = reinterpret_cast<const unsigned short*>(&v[ks]);
        union { uint4v w; short8v s; } pk;
#pragma unroll
        for (int p = 0; p < 4; ++p) {
            float h0 = fmaxf(bf2f(up[2 * p])     + bf2f(vp[2 * p]),     0.f);
            float h1 = fmaxf(bf2f(up[2 * p + 1]) + bf2f(vp[2 * p + 1]), 0.f);
            unsigned r;
            asm("v_cvt_pk_bf16_f32 %0, %1, %2" : "=v"(r) : "v"(h0), "v"(h1));
            pk.w[p] = r;
        }
        pa[ks] = pk.s;
    }

    float4v acc = (float4v){0.f, 0.f, 0.f, 0.f};
#pragma unroll
    for (int ks = 0; ks < 4; ++ks)
        acc = __builtin_amdgcn_mfma_f32_16x16x32_bf16(wb[ks], pa[ks], acc, 0, 0, 0);

    // D: col = lane&15 = edge, row = lk*4 + r -> rows 0,1 live on lk==0
    if (lk == 0 && e < nEdges) {
        float dlt = (acc[1] + bb1) - (acc[0] + bb0);
        float a0 = 1.f / (1.f + __expf(dlt));
        out[e] = a0;
        out[(size_t)nEdges + e] = 1.f - a0;
    }
}

__global__ __launch_bounds__(256) void detect_only(
    const int* __restrict__ eidx, int nPairs, int* __restrict__ flag)
{
    detect_body(eidx, nPairs, flag);
}

// Last-resort fallback: compute h directly per edge.
__global__ __launch_bounds__(256) void edge_attn_direct(
    const int* __restrict__ eidx, const float* __restrict__ X,
    const float* __restrict__ W1, const float* __restrict__ b1,
    const float* __restrict__ W2, const float* __restrict__ b2,
    const int* __restrict__ i64flag, float* __restrict__ out,
    int nEdges, int nNodes)
{
    const int t = threadIdx.x;
    const int lane = t & 31;
    const int e = blockIdx.x * 8 + (t >> 5);
    if (e >= nEdges) return;
    const int is64 = i64flag ? *i64flag : 0;
    size_t sOff = is64 ? (size_t)2 * e : (size_t)e;
    size_t dOff = is64 ? (size_t)2 * ((size_t)nEdges + e) : (size_t)nEdges + e;
    int si = min(max(eidx[sOff], 0), nNodes - 1);
    int di = min(max(eidx[dOff], 0), nNodes - 1);

    const int j0 = lane * 4;
    float4 bv = *reinterpret_cast<const float4*>(b1 + j0);
    float a0 = bv.x, a1 = bv.y, a2 = bv.z, a3 = bv.w;
    const float* xs = X + (size_t)si * D;
    const float* xd = X + (size_t)di * D;
    for (int k = 0; k < 128; ++k) {
        float s = xs[k];
        float4 w = *reinterpret_cast<const float4*>(W1 + (size_t)k * D + j0);
        a0 += s * w.x; a1 += s * w.y; a2 += s * w.z; a3 += s * w.w;
        float d = xd[k];
        float4 w2r = *reinterpret_cast<const float4*>(W1 + (size_t)(k + 128) * D + j0);
        a0 += d * w2r.x; a1 += d * w2r.y; a2 += d * w2r.z; a3 += d * w2r.w;
    }
    a0 = fmaxf(a0, 0.f); a1 = fmaxf(a1, 0.f); a2 = fmaxf(a2, 0.f); a3 = fmaxf(a3, 0.f);
    float4 wa = *reinterpret_cast<const float4*>(W2 + j0 * 2);
    float4 wb = *reinterpret_cast<const float4*>(W2 + j0 * 2 + 4);
    float s0 = a0 * wa.x + a1 * wa.z + a2 * wb.x + a3 * wb.z;
    float s1 = a0 * wa.y + a1 * wa.w + a2 * wb.y + a3 * wb.w;
#pragma unroll
    for (int m = 16; m; m >>= 1) {
        s0 += __shfl_xor(s0, m);
        s1 += __shfl_xor(s1, m);
    }
    if (lane == 0) {
        s0 += b2[0]; s1 += b2[1];
        float mx = fmaxf(s0, s1);
        float e0 = __expf(s0 - mx), e1 = __expf(s1 - mx);
        float r = 1.f / (e0 + e1);
        out[e] = e0 * r;
        out[(size_t)nEdges + e] = e1 * r;
    }
}

extern "C" void kernel_launch(void* const* d_in, const int* in_sizes, int n_in,
                              void* d_out, int out_size, void* d_ws, size_t ws_size,
                              hipStream_t stream)
{
    const float* X   = (const float*)d_in[0];
    const int*   eix = (const int*)d_in[1];
    const float* W1  = (const float*)d_in[2];
    const float* b1  = (const float*)d_in[3];
    const float* W2  = (const float*)d_in[4];
    const float* b2  = (const float*)d_in[5];
    float* out = (float*)d_out;

    const int nNodes = in_sizes[0] / D;
    const int nEdges = in_sizes[1] / 2;
    const size_t uvElems = (size_t)nNodes * D;
    const size_t uvBytes = uvElems * sizeof(unsigned short);
    const size_t bcBytes = 256 * D * sizeof(unsigned short);   // 64 KB
    const size_t w2bBytes = 16 * D * sizeof(unsigned short);   // 4 KB
    const size_t xbBytes = uvElems * sizeof(unsigned short);
    const int nbEdge = (nEdges + 63) / 64;                     // 64 edges/block

    if (ws_size >= bcBytes + w2bBytes + xbBytes + 2 * uvBytes + 16) {
        // tier 1: Bc | W2b | Xb | U | V | flag
        unsigned short* Bc  = (unsigned short*)d_ws;
        unsigned short* W2b = (unsigned short*)((char*)d_ws + bcBytes);
        unsigned short* Xb  = (unsigned short*)((char*)d_ws + bcBytes + w2bBytes);
        unsigned short* U   = (unsigned short*)((char*)d_ws + bcBytes + w2bBytes + xbBytes);
        unsigned short* V   = U + uvElems;
        int* flag = (int*)((char*)d_ws + bcBytes + w2bBytes + xbBytes + 2 * uvBytes);
        const int nChunks = (int)(uvElems / 8);
        prep<<<129 + (nChunks + 255) / 256, 256, 0, stream>>>(
            X, W1, W2, Bc, W2b, Xb, eix, nEdges, flag, nChunks);
        uv_mfma<<<(nNodes + 63) / 64, 256, 0, stream>>>(Xb, Bc, b1, U, V, nNodes);
        edge_attn<<<nbEdge, 256, 0, stream>>>(eix, U, V, W2b, b2, flag, out, nEdges, nNodes);
    } else if (ws_size >= bcBytes + w2bBytes + 2 * uvBytes + 16) {
        // tier 2: Bc | W2b | U | V | flag
        unsigned short* Bc  = (unsigned short*)d_ws;
        unsigned short* W2b = (unsigned short*)((char*)d_ws + bcBytes);
        unsigned short* U   = (unsigned short*)((char*)d_ws + bcBytes + w2bBytes);
        unsigned short* V   = U + uvElems;
        int* flag = (int*)((char*)d_ws + bcBytes + w2bBytes + 2 * uvBytes);
        prep<<<129, 256, 0, stream>>>(X, W1, W2, Bc, W2b, nullptr, eix, nEdges, flag, 0);
        uv_mfma_f32<<<(nNodes + 63) / 64, 256, 0, stream>>>(X, Bc, b1, U, V, nNodes);
        edge_attn<<<nbEdge, 256, 0, stream>>>(eix, U, V, W2b, b2, flag, out, nEdges, nNodes);
    } else {
        int* flag = (ws_size >= 4) ? (int*)d_ws : nullptr;
        if (flag) detect_only<<<1, 256, 0, stream>>>(eix, nEdges, flag);
        const int nb = (nEdges + 7) / 8;
        edge_attn_direct<<<nb, 256, 0, stream>>>(eix, X, W1, b1, W2, b2, flag, out, nEdges, nNodes);
    }
}

// Round 9
// 177.082 us; speedup vs baseline: 1.0485x; 1.0485x over previous
//
#include <hip/hip_runtime.h>
#include <hip/hip_bf16.h>
#include <cstdint>

#define D 128

typedef __attribute__((ext_vector_type(8))) short short8v;
typedef __attribute__((ext_vector_type(4))) float float4v;
typedef __attribute__((ext_vector_type(4))) unsigned int uint4v;

__device__ __forceinline__ float bf2f(unsigned short u) {
    union { unsigned int i; float f; } x; x.i = ((unsigned int)u) << 16; return x.f;
}
__device__ __forceinline__ unsigned short f2bf(float f) {
    union { float f; unsigned int i; } x; x.f = f;
    unsigned int r = x.i + 0x7FFFu + ((x.i >> 16) & 1u);
    return (unsigned short)(r >> 16);
}

__device__ __forceinline__ void detect_body(const int* __restrict__ eidx, int nPairs,
                                            int* __restrict__ flag) {
    __shared__ int anyNZ;
    if (threadIdx.x == 0) anyNZ = 0;
    __syncthreads();
    int cnt = nPairs < 2048 ? nPairs : 2048;
    int local = 0;
    for (int i = threadIdx.x; i < cnt; i += 256)
        if (eidx[2 * i + 1] != 0) local = 1;
    if (local) anyNZ = 1;
    __syncthreads();
    if (threadIdx.x == 0) *flag = (anyNZ == 0) ? 1 : 0;
}

// blocks 0..127: W1 (fp32) -> Bc (bf16 [n=256][k=128]);
// block 128: int64-layout detect;
// blocks 129..: X (fp32) -> Xb (bf16), streaming.
__global__ __launch_bounds__(256) void prep(
    const float* __restrict__ X, const float* __restrict__ W1,
    unsigned short* __restrict__ Bc, unsigned short* __restrict__ Xb,
    const int* __restrict__ eidx, int nPairs, int* __restrict__ flag, int nChunks)
{
    const int b = blockIdx.x;
    if (b < 128) {
        int i = b * 256 + threadIdx.x;
        int n = i >> 7, k = i & 127;
        Bc[i] = f2bf(W1[(size_t)((n < 128) ? k : k + 128) * D + (n & 127)]);
    } else if (b == 128) {
        detect_body(eidx, nPairs, flag);
    } else {
        int c = (b - 129) * 256 + threadIdx.x;
        if (c < nChunks) {
            const float* p = X + (size_t)c * 8;
            float4 x0 = *reinterpret_cast<const float4*>(p);
            float4 x1 = *reinterpret_cast<const float4*>(p + 4);
            short8v o;
            o[0] = (short)f2bf(x0.x); o[1] = (short)f2bf(x0.y);
            o[2] = (short)f2bf(x0.z); o[3] = (short)f2bf(x0.w);
            o[4] = (short)f2bf(x1.x); o[5] = (short)f2bf(x1.y);
            o[6] = (short)f2bf(x1.z); o[7] = (short)f2bf(x1.w);
            *reinterpret_cast<short8v*>(Xb + (size_t)c * 8) = o;
        }
    }
}

// U|V = Xb @ W1 via bf16 MFMA, swapped operands; 64 nodes x 256 cols per block.
// B force-hoisted, A depth-1 prefetched, b1 folded into acc init.
__global__ __launch_bounds__(256, 4) void uv_mfma(
    const unsigned short* __restrict__ Xb, const unsigned short* __restrict__ Bc,
    const float* __restrict__ b1,
    unsigned short* __restrict__ U, unsigned short* __restrict__ V, int nNodes)
{
    const int t = threadIdx.x;
    const int wave = t >> 6;
    const int l = t & 63;
    const int lr = l & 15;          // node lane / B-col lane
    const int lk = l >> 4;          // k-group lane
    const int n0w = wave * 64;      // this wave's output-col base (0..255)

    short8v bf[4][4];
#pragma unroll
    for (int nt = 0; nt < 4; ++nt)
#pragma unroll
        for (int ks = 0; ks < 4; ++ks)
            bf[nt][ks] = *reinterpret_cast<const short8v*>(
                Bc + (size_t)(n0w + nt * 16 + lr) * D + ks * 32 + lk * 8);
#pragma unroll
    for (int nt = 0; nt < 4; ++nt)
#pragma unroll
        for (int ks = 0; ks < 4; ++ks)
            asm volatile("" : "+v"(bf[nt][ks]));

    // bias for this lane's output cols (0 for V-columns); folded into acc init
    float4 bvv[4];
#pragma unroll
    for (int nt = 0; nt < 4; ++nt) {
        if (n0w < 128)
            bvv[nt] = *reinterpret_cast<const float4*>(b1 + n0w + nt * 16 + lk * 4);
        else
            bvv[nt] = make_float4(0.f, 0.f, 0.f, 0.f);
    }

    int row = blockIdx.x * 64 + lr;
    const unsigned short* xbase = Xb + lk * 8;

    short8v aC[4], aN[4];
    {
        const unsigned short* p = xbase + (size_t)min(row, nNodes - 1) * D;
#pragma unroll
        for (int ks = 0; ks < 4; ++ks)
            aC[ks] = *reinterpret_cast<const short8v*>(p + ks * 32);
    }

#pragma unroll
    for (int mt = 0; mt < 4; ++mt) {
        if (mt < 3) {
            const unsigned short* p = xbase + (size_t)min(row + 16, nNodes - 1) * D;
#pragma unroll
            for (int ks = 0; ks < 4; ++ks)
                aN[ks] = *reinterpret_cast<const short8v*>(p + ks * 32);
        }
        float4v acc[4];
#pragma unroll
        for (int nt = 0; nt < 4; ++nt) {
            acc[nt] = (float4v){bvv[nt].x, bvv[nt].y, bvv[nt].z, bvv[nt].w};
#pragma unroll
            for (int ks = 0; ks < 4; ++ks)
                acc[nt] = __builtin_amdgcn_mfma_f32_16x16x32_bf16(
                    bf[nt][ks], aC[ks], acc[nt], 0, 0, 0);
        }
        if (row < nNodes) {
            unsigned short* base = (n0w < 128 ? U : V) + (size_t)row * D + (n0w & 127);
#pragma unroll
            for (int nt = 0; nt < 4; ++nt) {
                ushort4 o;
                o.x = f2bf(acc[nt][0]); o.y = f2bf(acc[nt][1]);
                o.z = f2bf(acc[nt][2]); o.w = f2bf(acc[nt][3]);
                *reinterpret_cast<ushort4*>(base + nt * 16 + lk * 4) = o;
            }
        }
        row += 16;
#pragma unroll
        for (int ks = 0; ks < 4; ++ks) aC[ks] = aN[ks];
    }
}

// Mid-tier fallback (no Xb): fp32 X + in-kernel cvt, b1 folded.
__global__ __launch_bounds__(256, 3) void uv_mfma_f32(
    const float* __restrict__ X, const unsigned short* __restrict__ Bc,
    const float* __restrict__ b1,
    unsigned short* __restrict__ U, unsigned short* __restrict__ V, int nNodes)
{
    const int t = threadIdx.x;
    const int wave = t >> 6;
    const int l = t & 63;
    const int lr = l & 15;
    const int lk = l >> 4;
    const int n0w = wave * 64;

    short8v bf[4][4];
#pragma unroll
    for (int nt = 0; nt < 4; ++nt)
#pragma unroll
        for (int ks = 0; ks < 4; ++ks)
            bf[nt][ks] = *reinterpret_cast<const short8v*>(
                Bc + (size_t)(n0w + nt * 16 + lr) * D + ks * 32 + lk * 8);

    float4 bvv[4];
#pragma unroll
    for (int nt = 0; nt < 4; ++nt) {
        if (n0w < 128)
            bvv[nt] = *reinterpret_cast<const float4*>(b1 + n0w + nt * 16 + lk * 4);
        else
            bvv[nt] = make_float4(0.f, 0.f, 0.f, 0.f);
    }

    int row = blockIdx.x * 64 + lr;
    float4 xr[8];
    {
        const float* xp = X + (size_t)min(row, nNodes - 1) * D + lk * 8;
#pragma unroll
        for (int ks = 0; ks < 4; ++ks) {
            xr[2 * ks]     = *reinterpret_cast<const float4*>(xp + ks * 32);
            xr[2 * ks + 1] = *reinterpret_cast<const float4*>(xp + ks * 32 + 4);
        }
    }
#pragma unroll
    for (int mt = 0; mt < 4; ++mt) {
        short8v af[4];
#pragma unroll
        for (int ks = 0; ks < 4; ++ks) {
            const float4 x0 = xr[2 * ks], x1 = xr[2 * ks + 1];
            short8v a;
            a[0] = (short)f2bf(x0.x); a[1] = (short)f2bf(x0.y);
            a[2] = (short)f2bf(x0.z); a[3] = (short)f2bf(x0.w);
            a[4] = (short)f2bf(x1.x); a[5] = (short)f2bf(x1.y);
            a[6] = (short)f2bf(x1.z); a[7] = (short)f2bf(x1.w);
            af[ks] = a;
        }
        if (mt < 3) {
            const float* np = X + (size_t)min(row + 16, nNodes - 1) * D + lk * 8;
#pragma unroll
            for (int ks = 0; ks < 4; ++ks) {
                xr[2 * ks]     = *reinterpret_cast<const float4*>(np + ks * 32);
                xr[2 * ks + 1] = *reinterpret_cast<const float4*>(np + ks * 32 + 4);
            }
        }
        float4v acc[4];
#pragma unroll
        for (int nt = 0; nt < 4; ++nt) {
            acc[nt] = (float4v){bvv[nt].x, bvv[nt].y, bvv[nt].z, bvv[nt].w};
#pragma unroll
            for (int ks = 0; ks < 4; ++ks)
                acc[nt] = __builtin_amdgcn_mfma_f32_16x16x32_bf16(
                    bf[nt][ks], af[ks], acc[nt], 0, 0, 0);
        }
        if (row < nNodes) {
            unsigned short* base = (n0w < 128 ? U : V) + (size_t)row * D + (n0w & 127);
#pragma unroll
            for (int nt = 0; nt < 4; ++nt) {
                ushort4 o;
                o.x = f2bf(acc[nt][0]); o.y = f2bf(acc[nt][1]);
                o.z = f2bf(acc[nt][2]); o.w = f2bf(acc[nt][3]);
                *reinterpret_cast<ushort4*>(base + nt * 16 + lk * 4) = o;
            }
        }
        row += 16;
    }
}

// One edge per 16 lanes (8 dims/lane, 16B gathers), 8 edges per group.
// ALL 16 gathers pinned in flight by a SINGLE asm barrier (one consumption
// point -> every load issues before any waitcnt). b1 pre-folded into U;
// softmax-over-2 as sigmoid.
__global__ __launch_bounds__(256, 4) void edge_attn(
    const int* __restrict__ eidx, const unsigned short* __restrict__ U,
    const unsigned short* __restrict__ V,
    const float* __restrict__ W2, const float* __restrict__ b2,
    const int* __restrict__ i64flag, float* __restrict__ out,
    int nEdges, int nNodes)
{
    const int t = threadIdx.x;
    const int g = t >> 4;
    const int lane = t & 15;
    const int ebase = (blockIdx.x * 16 + g) * 8;
    if (ebase >= nEdges) return;
    const int is64 = *i64flag;
    const bool vec = ((nEdges & 7) == 0);

    // hoisted uniforms (independent of gathers)
    float4 w0 = *reinterpret_cast<const float4*>(W2 + lane * 16);
    float4 w1 = *reinterpret_cast<const float4*>(W2 + lane * 16 + 4);
    float4 w2 = *reinterpret_cast<const float4*>(W2 + lane * 16 + 8);
    float4 w3 = *reinterpret_cast<const float4*>(W2 + lane * 16 + 12);
    const float bb0 = b2[0], bb1 = b2[1];

    int si[8], di[8];
    if (vec) {
        if (!is64) {
            int4 a = *reinterpret_cast<const int4*>(eidx + ebase);
            int4 b = *reinterpret_cast<const int4*>(eidx + ebase + 4);
            int4 c = *reinterpret_cast<const int4*>(eidx + (size_t)nEdges + ebase);
            int4 d = *reinterpret_cast<const int4*>(eidx + (size_t)nEdges + ebase + 4);
            si[0] = a.x; si[1] = a.y; si[2] = a.z; si[3] = a.w;
            si[4] = b.x; si[5] = b.y; si[6] = b.z; si[7] = b.w;
            di[0] = c.x; di[1] = c.y; di[2] = c.z; di[3] = c.w;
            di[4] = d.x; di[5] = d.y; di[6] = d.z; di[7] = d.w;
        } else {
#pragma unroll
            for (int q = 0; q < 4; ++q) {
                int4 a = *reinterpret_cast<const int4*>(eidx + 2 * (size_t)ebase + 4 * q);
                si[2 * q] = a.x; si[2 * q + 1] = a.z;
                int4 c = *reinterpret_cast<const int4*>(
                    eidx + 2 * ((size_t)nEdges + ebase) + 4 * q);
                di[2 * q] = c.x; di[2 * q + 1] = c.z;
            }
        }
    } else {
#pragma unroll
        for (int i = 0; i < 8; ++i) {
            int e = ebase + i; if (e >= nEdges) e = nEdges - 1;
            size_t sOff = is64 ? (size_t)2 * e : (size_t)e;
            size_t dOff = is64 ? (size_t)2 * ((size_t)nEdges + e) : (size_t)nEdges + e;
            si[i] = eidx[sOff];
            di[i] = eidx[dOff];
        }
    }
    const unsigned nmax = (unsigned)(nNodes - 1);
    const unsigned lane16 = (unsigned)lane << 4;
    // issue all 16 gathers (32-bit byte offsets)
    uint4v u[8], v[8];
#pragma unroll
    for (int i = 0; i < 8; ++i) {
        unsigned off = (min((unsigned)si[i], nmax) << 8) + lane16;
        u[i] = *reinterpret_cast<const uint4v*>((const char*)U + off);
    }
#pragma unroll
    for (int i = 0; i < 8; ++i) {
        unsigned off = (min((unsigned)di[i], nmax) << 8) + lane16;
        v[i] = *reinterpret_cast<const uint4v*>((const char*)V + off);
    }
    // SINGLE pin: all 16 loads must be issued before this point, and no
    // consumption (waitcnt) can be scheduled between the issues.
    asm volatile(""
        : "+v"(u[0]), "+v"(u[1]), "+v"(u[2]), "+v"(u[3]),
          "+v"(u[4]), "+v"(u[5]), "+v"(u[6]), "+v"(u[7]),
          "+v"(v[0]), "+v"(v[1]), "+v"(v[2]), "+v"(v[3]),
          "+v"(v[4]), "+v"(v[5]), "+v"(v[6]), "+v"(v[7]));

    const float wc[16] = {w0.x, w0.y, w0.z, w0.w, w1.x, w1.y, w1.z, w1.w,
                          w2.x, w2.y, w2.z, w2.w, w3.x, w3.y, w3.z, w3.w};

#pragma unroll
    for (int i = 0; i < 8; ++i) {
        const unsigned short* up = reinterpret_cast<const unsigned short*>(&u[i]);
        const unsigned short* vp = reinterpret_cast<const unsigned short*>(&v[i]);
        float s0 = 0.f, s1 = 0.f;
#pragma unroll
        for (int j = 0; j < 8; ++j) {
            float h = fmaxf(bf2f(up[j]) + bf2f(vp[j]), 0.f);   // b1 pre-folded into U
            s0 += h * wc[2 * j];
            s1 += h * wc[2 * j + 1];
        }
#pragma unroll
        for (int m = 8; m; m >>= 1) {
            s0 += __shfl_xor(s0, m);
            s1 += __shfl_xor(s1, m);
        }
        if (lane == 0 && ebase + i < nEdges) {
            const int e = ebase + i;
            float dlt = (s1 + bb1) - (s0 + bb0);
            float e1 = __expf(dlt);
            float a0 = 1.f / (1.f + e1);
            out[e] = a0;
            out[(size_t)nEdges + e] = 1.f - a0;
        }
    }
}

__global__ __launch_bounds__(256) void detect_only(
    const int* __restrict__ eidx, int nPairs, int* __restrict__ flag)
{
    detect_body(eidx, nPairs, flag);
}

// Last-resort fallback: compute h directly per edge.
__global__ __launch_bounds__(256) void edge_attn_direct(
    const int* __restrict__ eidx, const float* __restrict__ X,
    const float* __restrict__ W1, const float* __restrict__ b1,
    const float* __restrict__ W2, const float* __restrict__ b2,
    const int* __restrict__ i64flag, float* __restrict__ out,
    int nEdges, int nNodes)
{
    const int t = threadIdx.x;
    const int lane = t & 31;
    const int e = blockIdx.x * 8 + (t >> 5);
    if (e >= nEdges) return;
    const int is64 = i64flag ? *i64flag : 0;
    size_t sOff = is64 ? (size_t)2 * e : (size_t)e;
    size_t dOff = is64 ? (size_t)2 * ((size_t)nEdges + e) : (size_t)nEdges + e;
    int si = min(max(eidx[sOff], 0), nNodes - 1);
    int di = min(max(eidx[dOff], 0), nNodes - 1);

    const int j0 = lane * 4;
    float4 bv = *reinterpret_cast<const float4*>(b1 + j0);
    float a0 = bv.x, a1 = bv.y, a2 = bv.z, a3 = bv.w;
    const float* xs = X + (size_t)si * D;
    const float* xd = X + (size_t)di * D;
    for (int k = 0; k < 128; ++k) {
        float s = xs[k];
        float4 w = *reinterpret_cast<const float4*>(W1 + (size_t)k * D + j0);
        a0 += s * w.x; a1 += s * w.y; a2 += s * w.z; a3 += s * w.w;
        float d = xd[k];
        float4 w2r = *reinterpret_cast<const float4*>(W1 + (size_t)(k + 128) * D + j0);
        a0 += d * w2r.x; a1 += d * w2r.y; a2 += d * w2r.z; a3 += d * w2r.w;
    }
    a0 = fmaxf(a0, 0.f); a1 = fmaxf(a1, 0.f); a2 = fmaxf(a2, 0.f); a3 = fmaxf(a3, 0.f);
    float4 wa = *reinterpret_cast<const float4*>(W2 + j0 * 2);
    float4 wb = *reinterpret_cast<const float4*>(W2 + j0 * 2 + 4);
    float s0 = a0 * wa.x + a1 * wa.z + a2 * wb.x + a3 * wb.z;
    float s1 = a0 * wa.y + a1 * wa.w + a2 * wb.y + a3 * wb.w;
#pragma unroll
    for (int m = 16; m; m >>= 1) {
        s0 += __shfl_xor(s0, m);
        s1 += __shfl_xor(s1, m);
    }
    if (lane == 0) {
        s0 += b2[0]; s1 += b2[1];
        float mx = fmaxf(s0, s1);
        float e0 = __expf(s0 - mx), e1 = __expf(s1 - mx);
        float r = 1.f / (e0 + e1);
        out[e] = e0 * r;
        out[(size_t)nEdges + e] = e1 * r;
    }
}

extern "C" void kernel_launch(void* const* d_in, const int* in_sizes, int n_in,
                              void* d_out, int out_size, void* d_ws, size_t ws_size,
                              hipStream_t stream)
{
    const float* X   = (const float*)d_in[0];
    const int*   eix = (const int*)d_in[1];
    const float* W1  = (const float*)d_in[2];
    const float* b1  = (const float*)d_in[3];
    const float* W2  = (const float*)d_in[4];
    const float* b2  = (const float*)d_in[5];
    float* out = (float*)d_out;

    const int nNodes = in_sizes[0] / D;
    const int nEdges = in_sizes[1] / 2;
    const size_t uvElems = (size_t)nNodes * D;
    const size_t uvBytes = uvElems * sizeof(unsigned short);
    const size_t bcBytes = 256 * D * sizeof(unsigned short);   // 64 KB
    const size_t xbBytes = uvElems * sizeof(unsigned short);
    const int nbEdge8 = (nEdges + 127) / 128;

    if (ws_size >= bcBytes + xbBytes + 2 * uvBytes + 16) {
        // tier 1: Bc | Xb | U | V | flag
        unsigned short* Bc = (unsigned short*)d_ws;
        unsigned short* Xb = (unsigned short*)((char*)d_ws + bcBytes);
        unsigned short* U  = (unsigned short*)((char*)d_ws + bcBytes + xbBytes);
        unsigned short* V  = U + uvElems;
        int* flag = (int*)((char*)d_ws + bcBytes + xbBytes + 2 * uvBytes);
        const int nChunks = (int)(uvElems / 8);
        prep<<<129 + (nChunks + 255) / 256, 256, 0, stream>>>(
            X, W1, Bc, Xb, eix, nEdges, flag, nChunks);
        uv_mfma<<<(nNodes + 63) / 64, 256, 0, stream>>>(Xb, Bc, b1, U, V, nNodes);
        edge_attn<<<nbEdge8, 256, 0, stream>>>(eix, U, V, W2, b2, flag, out, nEdges, nNodes);
    } else if (ws_size >= bcBytes + 2 * uvBytes + 16) {
        // tier 2: Bc | U | V | flag
        unsigned short* Bc = (unsigned short*)d_ws;
        unsigned short* U  = (unsigned short*)((char*)d_ws + bcBytes);
        unsigned short* V  = U + uvElems;
        int* flag = (int*)((char*)d_ws + bcBytes + 2 * uvBytes);
        prep<<<129, 256, 0, stream>>>(X, W1, Bc, nullptr, eix, nEdges, flag, 0);
        uv_mfma_f32<<<(nNodes + 63) / 64, 256, 0, stream>>>(X, Bc, b1, U, V, nNodes);
        edge_attn<<<nbEdge8, 256, 0, stream>>>(eix, U, V, W2, b2, flag, out, nEdges, nNodes);
    } else {
        int* flag = (ws_size >= 4) ? (int*)d_ws : nullptr;
        if (flag) detect_only<<<1, 256, 0, stream>>>(eix, nEdges, flag);
        const int nbEdge = (nEdges + 7) / 8;
        edge_attn_direct<<<nbEdge, 256, 0, stream>>>(eix, X, W1, b1, W2, b2, flag, out, nEdges, nNodes);
    }
}